// Round 13
// baseline (329.912 us; speedup 1.0000x reference)
//
#include <hip/hip_runtime.h>
#include <hip/hip_bf16.h>

// Problem constants (fixed by the reference).
constexpr int T  = 4096;   // contraction dim (K = t)
constexpr int Bb = 8;      // batch
constexpr int C  = 512;    // channels (N)
constexpr int S  = 2048;   // groups (M)
constexpr int BC = Bb * C; // 4096 floats: t-row stride of x, s-row stride of out

constexpr int BK = 32;        // K-tile staged per iteration
constexpr int NK = T / BK;    // 128 iterations

typedef __bf16 bf16x8 __attribute__((ext_vector_type(8)));
typedef float  f32x16 __attribute__((ext_vector_type(16)));
typedef float  f32x4  __attribute__((ext_vector_type(4)));

// pack two f32 -> one dword of 2x bf16 (lo = first, hi = second), RNE.
__device__ inline unsigned pk2(float lo, float hi) {
    union { __hip_bfloat16 h; unsigned short u; } a, b;
    a.h = __float2bfloat16(lo);
    b.h = __float2bfloat16(hi);
    return ((unsigned)b.u << 16) | (unsigned)a.u;
}

// 16B-slot swizzle, bijective within each 32-slot group; spreads the
// strided staging writes across bank groups while fragment reads stay a
// lane-permuted contiguous region.
__device__ inline int slot16(int s) { return s ^ ((s >> 2) & 7); }

// out[0,b,c] = leftmost[c]
__global__ void left_fill(const float* __restrict__ left, float* __restrict__ out) {
    int i = blockIdx.x * blockDim.x + threadIdx.x;   // 0..BC-1
    if (i < BC) out[i] = left[i & (C - 1)];
}

// Per-b GEMM: out[(s+1),b,c] = sum_t mask[b,t,s] * x[t,b,c].
// ROUND-13: 4 INDEPENDENT BARRIER DOMAINS PER CU (was 2 since r4; five
// structural edits at 2 domains were all neutral -> the binding constraint
// is inter-domain latency overlap, not per-wave efficiency or barriers).
// Block 256 thr = 4 waves, tile 128(s) x 64(c), BK=32, dbuf LDS.
// Waves: h = wave>>1 K-half split (h=0: t0-15, h=1: t16-31 of each tile),
// wm = wave&1 s-half. Wave tile 64x64 -> 4 ds_read_b128 : 4 MFMA (1:1).
// Grid 1024 = 4 blocks/CU (16 waves/CU), LDS 32KB/block = 128KB/CU.
// NO depth-2 prefetch (r7/r10 lesson: it spills at 128-VGPR cap).
// XCD swizzle: b = bid&7; ALL 128 blocks of a batch plane are resident on
// one XCD simultaneously (4/CU x 32 CU) -> the x8 nt-sharers of each mask
// panel and x16 mt-sharers of each x panel hit L2 in a tight window.
// Epilogue: h=1 waves dump acc to LDS; h=0 waves add + store (r6 pattern).
__global__ __launch_bounds__(256, 4) void ds_gemm(
    const float* __restrict__ x,
    const float* __restrict__ mask,
    float* __restrict__ out)
{
    __shared__ __align__(16) unsigned char smem[32768];  // loop: 2 x 12KB; epi: 2 x 16KB

    // ---- chunked XCD swizzle (bijective: 1024 = 8 xcd * 128 slots) ----
    const int bid0 = blockIdx.x;
    const int xcd  = bid0 & 7;            // HW XCD of this block (round-robin)
    const int slot = bid0 >> 3;           // 0..127 within this XCD
    const int b    = xcd;                 // batch plane owned by this XCD
    const int mt   = slot & 15;           // s-tile (128 rows)
    const int nt   = slot >> 4;           // c-tile (0..7, 64 cols)

    const int tid  = threadIdx.x;
    const int lane = tid & 63;
    const int wave = tid >> 6;       // 0..3
    const int h    = wave >> 1;      // K-half (0..1)
    const int wm   = wave & 1;       // s-half (0..1)
    const int lm = lane & 31;
    const int kg = lane >> 5;

    // ---------------- staging roles (wave-aligned)
    // thr 0-127 (waves 0-1): A = mask tile 128s x 32t  (4096 f32, 32/thread)
    // thr 128-191 (wave 2):  B = x    tile  64c x 32t  (2048 f32, 32/thread)
    // thr 192-255 (wave 3):  compute-only
    const bool stA = (tid < 128);
    const bool stG = (tid < 192);         // stages anything
    const int  ii  = stA ? tid : (tid - 128);
    const int  sg  = stA ? (ii & 31) : (ii & 15);   // 4-wide col group
    const int  tg  = stA ? (ii >> 5) : (ii >> 4);   // t-oct 0..3

    const float* gsrc = stA
        ? mask + (size_t)b * T * S + (size_t)(tg * 8) * S + mt * 128 + sg * 4
        : x    + (size_t)(tg * 8) * BC + b * C + nt * 64 + sg * 4;
    const size_t grow  = stA ? (size_t)S : (size_t)BC;  // floats per t-row
    const size_t gstep = grow * BK;                      // advance per K-tile

    int waddr[4];
#pragma unroll
    for (int j = 0; j < 4; ++j)
        waddr[j] = stA ? (tg * 2048 + slot16(sg * 4 + j) * 16)
                       : (8192 + tg * 1024 + slot16(sg * 4 + j) * 16);

    // ---------------- fragment read addresses (oct = h*2 + kg)
    int raddrA[2], raddrB[2];
#pragma unroll
    for (int q = 0; q < 2; ++q) {
        raddrA[q] = (h * 2 + kg) * 2048 + slot16(wm * 64 + q * 32 + lm) * 16;
        raddrB[q] = 8192 + (h * 2 + kg) * 1024 + slot16(q * 32 + lm) * 16;
    }

    f32x16 acc[2][2] = {};
    f32x4  L[8];

#define LOAD_TILE(k)                                                        \
    if (stG) {                                                              \
        const float* p_ = gsrc + (size_t)(k) * gstep;                       \
        _Pragma("unroll") for (int r = 0; r < 8; ++r)                       \
            L[r] = *(const f32x4*)(p_ + (size_t)r * grow);                  \
    }

#define WRITE_TILE(buf)                                                     \
    if (stG) {                                                              \
        const int boff_ = (buf) * 12288;                                    \
        _Pragma("unroll") for (int j = 0; j < 4; ++j) {                     \
            uint4 w_;                                                       \
            w_.x = pk2(L[0][j], L[1][j]);                                   \
            w_.y = pk2(L[2][j], L[3][j]);                                   \
            w_.z = pk2(L[4][j], L[5][j]);                                   \
            w_.w = pk2(L[6][j], L[7][j]);                                   \
            *(uint4*)(smem + boff_ + waddr[j]) = w_;                        \
        }                                                                   \
    }

#define COMPUTE(buf)                                                        \
    {                                                                       \
        const int boff_ = (buf) * 12288;                                    \
        bf16x8 a0_ = *(const bf16x8*)(smem + boff_ + raddrA[0]);            \
        bf16x8 a1_ = *(const bf16x8*)(smem + boff_ + raddrA[1]);            \
        bf16x8 b0_ = *(const bf16x8*)(smem + boff_ + raddrB[0]);            \
        bf16x8 b1_ = *(const bf16x8*)(smem + boff_ + raddrB[1]);            \
        acc[0][0] = __builtin_amdgcn_mfma_f32_32x32x16_bf16(a0_, b0_, acc[0][0], 0, 0, 0); \
        acc[0][1] = __builtin_amdgcn_mfma_f32_32x32x16_bf16(a0_, b1_, acc[0][1], 0, 0, 0); \
        acc[1][0] = __builtin_amdgcn_mfma_f32_32x32x16_bf16(a1_, b0_, acc[1][0], 0, 0, 0); \
        acc[1][1] = __builtin_amdgcn_mfma_f32_32x32x16_bf16(a1_, b1_, acc[1][1], 0, 0, 0); \
    }

    // Prologue: issue loads for tile 0.
    LOAD_TILE(0);

    // r8-validated loop: W(k)[vmcnt wait] -> issue loads(k+1) -> barrier ->
    // COMPUTE(k). Race: WRITE(k) -> buf k&1, last read COMPUTE(k-2),
    // barrier(k-1) between them -> single barrier/iter safe.
    for (int k = 0; k < NK; ++k) {
        WRITE_TILE(k & 1);
        if (k + 1 < NK) LOAD_TILE(k + 1);
        __syncthreads();
        COMPUTE(k & 1);
    }

#undef LOAD_TILE
#undef WRITE_TILE
#undef COMPUTE

    // -------- cross-K-half reduction via LDS, then store (h=0 waves only).
    // Wave w in {2,3} (h=1) dumps acc at region (w-2)*16KB; layout:
    // frag(m2,n2) 4KB + r-quad 1KB + lane*16B -> stride-1 float4.
    __syncthreads();                 // main-loop LDS reads done; safe to reuse
    if (h == 1) {
#pragma unroll
        for (int m2 = 0; m2 < 2; ++m2)
#pragma unroll
            for (int n2 = 0; n2 < 2; ++n2) {
                unsigned char* base = smem + (wave - 2) * 16384 + (m2 * 2 + n2) * 4096 + lane * 16;
#pragma unroll
                for (int r4 = 0; r4 < 4; ++r4) {
                    f32x4 v = { acc[m2][n2][r4 * 4 + 0], acc[m2][n2][r4 * 4 + 1],
                                acc[m2][n2][r4 * 4 + 2], acc[m2][n2][r4 * 4 + 3] };
                    *(f32x4*)(base + r4 * 1024) = v;
                }
            }
    }
    __syncthreads();
    if (h == 0) {
        // wave 0 (wm=0) pairs with wave 2 (region 0); wave 1 with wave 3 (region 1).
#pragma unroll
        for (int m2 = 0; m2 < 2; ++m2)
#pragma unroll
            for (int n2 = 0; n2 < 2; ++n2) {
                const unsigned char* base = smem + wave * 16384 + (m2 * 2 + n2) * 4096 + lane * 16;
#pragma unroll
                for (int r4 = 0; r4 < 4; ++r4) {
                    f32x4 v = *(const f32x4*)(base + r4 * 1024);
#pragma unroll
                    for (int j = 0; j < 4; ++j) acc[m2][n2][r4 * 4 + j] += v[j];
                }
            }

        // Store. C/D layout (HW-verified): col = lane&31,
        // row = (r&3) + 8*(r>>2) + 4*(lane>>5).
        const int s_w = mt * 128 + wm * 64;
        const int c_w = nt * 64;
        float* outp = out + BC;   // skip leftmost row
#pragma unroll
        for (int m2 = 0; m2 < 2; ++m2)
#pragma unroll
            for (int n2 = 0; n2 < 2; ++n2)
#pragma unroll
                for (int r = 0; r < 16; ++r) {
                    const int row  = (r & 3) + 8 * (r >> 2) + 4 * kg;
                    const int srow = s_w + m2 * 32 + row;
                    const int ccol = c_w + n2 * 32 + lm;
                    outp[(size_t)srow * BC + b * C + ccol] = acc[m2][n2][r];
                }
    }
}

extern "C" void kernel_launch(void* const* d_in, const int* in_sizes, int n_in,
                              void* d_out, int out_size, void* d_ws, size_t ws_size,
                              hipStream_t stream) {
    const float* x    = (const float*)d_in[0];  // [T,B,C] fp32
    const float* mask = (const float*)d_in[1];  // [B,T,S] fp32
    // d_in[2] = size_of_groups (int64) — unused by the 'average' reference path
    const float* left = (const float*)d_in[3];  // [1,1,C] fp32
    float* out = (float*)d_out;                 // [S+1,B,C] fp32

    left_fill<<<BC / 256, 256, 0, stream>>>(left, out);
    ds_gemm<<<Bb * (S / 128) * (C / 64), 256, 0, stream>>>(x, mask, out);
}

// Round 14
// 216.686 us; speedup vs baseline: 1.5225x; 1.5225x over previous
//
#include <hip/hip_runtime.h>
#include <hip/hip_bf16.h>

// Problem constants (fixed by the reference).
constexpr int T  = 4096;   // contraction dim (K = t)
constexpr int Bb = 8;      // batch
constexpr int C  = 512;    // channels (N)
constexpr int S  = 2048;   // groups (M)
constexpr int BC = Bb * C; // 4096 floats: t-row stride of x, s-row stride of out

constexpr int BK = 64;        // K-tile per iteration
constexpr int NK = T / BK;    // 64 iterations

typedef __bf16 bf16x8 __attribute__((ext_vector_type(8)));
typedef float  f32x16 __attribute__((ext_vector_type(16)));
typedef float  f32x4  __attribute__((ext_vector_type(4)));

__device__ inline unsigned pk2(float lo, float hi) {
    union { __hip_bfloat16 h; unsigned short u; } a, b;
    a.h = __float2bfloat16(lo);
    b.h = __float2bfloat16(hi);
    return ((unsigned)b.u << 16) | (unsigned)a.u;
}

__device__ inline int slot16(int s) { return s ^ ((s >> 2) & 7); }

// out[0,b,c] = leftmost[c]
__global__ void left_fill(const float* __restrict__ left, float* __restrict__ out) {
    int i = blockIdx.x * blockDim.x + threadIdx.x;
    if (i < BC) out[i] = left[i & (C - 1)];
}

// Pre-pass: xT[b][c][t] (bf16) = x[t][b][c]. 64x64 tiles via padded LDS.
// 4096 blocks x 256 thr; ~100MB traffic, BW-bound.
__global__ __launch_bounds__(256) void transpose_x(
    const float* __restrict__ x, __bf16* __restrict__ xT)
{
    __shared__ float lds[64][68];   // row stride 272B = 17x16B (b128-aligned)
    const int bid = blockIdx.x;
    const int b   = bid >> 9;          // 512 tiles per batch
    const int rem = bid & 511;
    const int t0  = (rem >> 3) * 64;   // 64 t-tiles
    const int c0  = (rem & 7) * 64;    // 8 c-tiles
    const int tid = threadIdx.x;

#pragma unroll
    for (int it = 0; it < 4; ++it) {
        const int slot = tid + it * 256;      // 1024 = 64 rows x 16 colgroups
        const int row = slot >> 4, cg = slot & 15;
        f32x4 v = *(const f32x4*)(x + (size_t)(t0 + row) * BC + b * C + c0 + cg * 4);
        *(f32x4*)(&lds[row][cg * 4]) = v;
    }
    __syncthreads();
#pragma unroll
    for (int it = 0; it < 2; ++it) {
        const int slot = tid + it * 256;      // 512 = 64 c-rows x 8 t-octs
        const int cr = slot >> 3, tg8 = slot & 7;
        uint4 w;
        w.x = pk2(lds[tg8 * 8 + 0][cr], lds[tg8 * 8 + 1][cr]);
        w.y = pk2(lds[tg8 * 8 + 2][cr], lds[tg8 * 8 + 3][cr]);
        w.z = pk2(lds[tg8 * 8 + 4][cr], lds[tg8 * 8 + 5][cr]);
        w.w = pk2(lds[tg8 * 8 + 6][cr], lds[tg8 * 8 + 7][cr]);
        *(uint4*)(xT + (size_t)(b * C + c0 + cr) * T + t0 + tg8 * 8) = w;
    }
}

// MAIN (round 14): r8 structure (128x128 tile, BK=64, 8 waves h-split K,
// 2 blocks/CU, XCD swizzle) but the B operand (x) is read DIRECTLY from
// pre-transposed bf16 xT[b][c][t]: one 16B global load per fragment --
// no LDS, no conversion, no staging regs for B. Only mask stages via LDS,
// spread over all 512 threads (16 f32 each -> L[4], half r8's pressure).
// Per iter: issue 4 B-frag loads (oldest) -> WRITE_A (vmcnt waits only the
// older A loads) -> issue A loads k+1 -> barrier -> COMPUTE.
// LDS loop footprint: A only, 2 x 16KB.
__global__ __launch_bounds__(512, 4) void ds_gemm_direct(
    const __bf16* __restrict__ xT,
    const float* __restrict__ mask,
    float* __restrict__ out)
{
    __shared__ __align__(16) unsigned char smem[65536];  // loop: 32KB; epilogue: 64KB

    const int bid0 = blockIdx.x;
    const int xcd  = bid0 & 7;
    const int slot = bid0 >> 3;
    const int b    = xcd;                 // batch plane owned by this XCD
    const int mt   = slot & 15;           // s-tile
    const int nt   = (slot >> 4) & 3;     // c-tile

    const int tid  = threadIdx.x;
    const int lane = tid & 63;
    const int wave = tid >> 6;       // 0..7
    const int h    = wave >> 2;      // K-group (0..1)
    const int wq   = wave & 3;
    const int wm = wq >> 1;          // s-half
    const int wn = wq & 1;           // c-half
    const int lm = lane & 31;
    const int kg = lane >> 5;

    // ---- A (mask) staging: ALL 512 threads, 4 t-rows x 4 s-cols each ----
    const int sg = tid & 31;         // 4-wide col group
    const int tq = tid >> 5;         // t-quad 0..15 (4 t-rows each)

    const float* gsrc = mask + (size_t)b * T * S + (size_t)(tq * 4) * S + mt * 128 + sg * 4;
    const size_t gstep = (size_t)S * BK;

    int waddr[4];
#pragma unroll
    for (int j = 0; j < 4; ++j)
        waddr[j] = (tq >> 1) * 2048 + slot16(sg * 4 + j) * 16 + (tq & 1) * 8;

    // ---- A fragment read addresses (oct = h*4 + kk*2 + kg) ----
    int raddrA[2][2];
#pragma unroll
    for (int kk = 0; kk < 2; ++kk)
#pragma unroll
        for (int q = 0; q < 2; ++q)
            raddrA[kk][q] = (h * 4 + kk * 2 + kg) * 2048 + slot16(wm * 64 + q * 32 + lm) * 16;

    // ---- B direct-from-global pointers (per n2 col) ----
    const __bf16* colptr[2];
#pragma unroll
    for (int n2 = 0; n2 < 2; ++n2)
        colptr[n2] = xT + (size_t)(b * C + nt * 128 + wn * 64 + n2 * 32 + lm) * T
                        + (h * 4 + kg) * 8;   // + kk*16 + k*64 at use

    f32x16 acc[2][2] = {};
    f32x4  L[4];
    bf16x8 Bf[2][2];

#define LOAD_A(k)                                                           \
    {                                                                       \
        const float* p_ = gsrc + (size_t)(k) * gstep;                       \
        _Pragma("unroll") for (int r = 0; r < 4; ++r)                       \
            L[r] = *(const f32x4*)(p_ + (size_t)r * S);                     \
    }

#define WRITE_A(buf)                                                        \
    {                                                                       \
        const int boff_ = (buf) * 16384;                                    \
        _Pragma("unroll") for (int j = 0; j < 4; ++j) {                     \
            uint2 w_;                                                       \
            w_.x = pk2(L[0][j], L[1][j]);                                   \
            w_.y = pk2(L[2][j], L[3][j]);                                   \
            *(uint2*)(smem + boff_ + waddr[j]) = w_;                        \
        }                                                                   \
    }

#define LOAD_B(k)                                                           \
    {                                                                       \
        _Pragma("unroll") for (int kk = 0; kk < 2; ++kk)                    \
        _Pragma("unroll") for (int n2 = 0; n2 < 2; ++n2)                    \
            Bf[kk][n2] = *(const bf16x8*)(colptr[n2] + (size_t)(k) * 64 + kk * 16); \
    }

#define COMPUTE(buf)                                                        \
    {                                                                       \
        const int boff_ = (buf) * 16384;                                    \
        _Pragma("unroll") for (int kk = 0; kk < 2; ++kk) {                  \
            bf16x8 a0_ = *(const bf16x8*)(smem + boff_ + raddrA[kk][0]);    \
            bf16x8 a1_ = *(const bf16x8*)(smem + boff_ + raddrA[kk][1]);    \
            acc[0][0] = __builtin_amdgcn_mfma_f32_32x32x16_bf16(a0_, Bf[kk][0], acc[0][0], 0, 0, 0); \
            acc[0][1] = __builtin_amdgcn_mfma_f32_32x32x16_bf16(a0_, Bf[kk][1], acc[0][1], 0, 0, 0); \
            acc[1][0] = __builtin_amdgcn_mfma_f32_32x32x16_bf16(a1_, Bf[kk][0], acc[1][0], 0, 0, 0); \
            acc[1][1] = __builtin_amdgcn_mfma_f32_32x32x16_bf16(a1_, Bf[kk][1], acc[1][1], 0, 0, 0); \
        }                                                                   \
    }

    LOAD_A(0);
    for (int k = 0; k < NK; ++k) {
        LOAD_B(k);                    // issued first: oldest VMEM this iter
        WRITE_A(k & 1);               // vmcnt wait hits only the OLDER A loads
        if (k + 1 < NK) LOAD_A(k + 1);
        __syncthreads();
        COMPUTE(k & 1);
        // Race: WRITE_A(k+2)->buf k&1 vs COMPUTE(k) reads: barrier(k+1) between.
    }

#undef LOAD_A
#undef WRITE_A
#undef LOAD_B
#undef COMPUTE

    // -------- cross-K-group reduction via LDS, then store (h=0 only) --------
    __syncthreads();
    if (h == 1) {
#pragma unroll
        for (int m2 = 0; m2 < 2; ++m2)
#pragma unroll
            for (int n2 = 0; n2 < 2; ++n2) {
                unsigned char* base = smem + (wave - 4) * 16384 + (m2 * 2 + n2) * 4096 + lane * 16;
#pragma unroll
                for (int r4 = 0; r4 < 4; ++r4) {
                    f32x4 v = { acc[m2][n2][r4 * 4 + 0], acc[m2][n2][r4 * 4 + 1],
                                acc[m2][n2][r4 * 4 + 2], acc[m2][n2][r4 * 4 + 3] };
                    *(f32x4*)(base + r4 * 1024) = v;
                }
            }
    }
    __syncthreads();
    if (h == 0) {
#pragma unroll
        for (int m2 = 0; m2 < 2; ++m2)
#pragma unroll
            for (int n2 = 0; n2 < 2; ++n2) {
                const unsigned char* base = smem + wave * 16384 + (m2 * 2 + n2) * 4096 + lane * 16;
#pragma unroll
                for (int r4 = 0; r4 < 4; ++r4) {
                    f32x4 v = *(const f32x4*)(base + r4 * 1024);
#pragma unroll
                    for (int j = 0; j < 4; ++j) acc[m2][n2][r4 * 4 + j] += v[j];
                }
            }
        const int s_w = mt * 128 + wm * 64;
        const int c_w = nt * 128 + wn * 64;
        float* outp = out + BC;
#pragma unroll
        for (int m2 = 0; m2 < 2; ++m2)
#pragma unroll
            for (int n2 = 0; n2 < 2; ++n2)
#pragma unroll
                for (int r = 0; r < 16; ++r) {
                    const int row  = (r & 3) + 8 * (r >> 2) + 4 * kg;
                    outp[(size_t)(s_w + m2 * 32 + row) * BC + b * C + c_w + n2 * 32 + lm]
                        = acc[m2][n2][r];
                }
    }
}

// ---------- FALLBACK (ws too small): round-8 champion kernel verbatim ----------
__global__ __launch_bounds__(512, 4) void ds_gemm_fb(
    const float* __restrict__ x, const float* __restrict__ mask, float* __restrict__ out)
{
    __shared__ __align__(16) unsigned char smem[65536];
    const int bid0 = blockIdx.x;
    const int xcd = bid0 & 7, slot = bid0 >> 3;
    const int b = xcd, mt = slot & 15, nt = (slot >> 4) & 3;
    const int tid = threadIdx.x, lane = tid & 63, wave = tid >> 6;
    const int h = wave >> 2, wq = wave & 3, wm = wq >> 1, wn = wq & 1;
    const int lm = lane & 31, kg = lane >> 5;
    const int ii = tid & 255, sg = ii & 31, tg = ii >> 5;
    const bool stB = (tid >= 256);
    const float* gsrc = stB
        ? x    + (size_t)(tg * 8) * BC + b * C + nt * 128 + sg * 4
        : mask + (size_t)b * T * S + (size_t)(tg * 8) * S + mt * 128 + sg * 4;
    const size_t grow = stB ? (size_t)BC : (size_t)S;
    const size_t gstep = grow * BK;
    int waddr[4];
#pragma unroll
    for (int j = 0; j < 4; ++j)
        waddr[j] = (stB ? 16384 : 0) + tg * 2048 + slot16(sg * 4 + j) * 16;
    int raddrA[2][2], raddrB[2][2];
#pragma unroll
    for (int kk = 0; kk < 2; ++kk)
#pragma unroll
        for (int q = 0; q < 2; ++q) {
            const int oct = h * 4 + kk * 2 + kg;
            raddrA[kk][q] = oct * 2048 + slot16(wm * 64 + q * 32 + lm) * 16;
            raddrB[kk][q] = 16384 + oct * 2048 + slot16(wn * 64 + q * 32 + lm) * 16;
        }
    f32x16 acc[2][2] = {};
    f32x4 L[8];
#define LOAD_TILE(k) { const float* p_ = gsrc + (size_t)(k) * gstep; \
    _Pragma("unroll") for (int r = 0; r < 8; ++r) L[r] = *(const f32x4*)(p_ + (size_t)r * grow); }
#define WRITE_TILE(buf) { const int boff_ = (buf) * 32768; \
    _Pragma("unroll") for (int j = 0; j < 4; ++j) { uint4 w_; \
        w_.x = pk2(L[0][j], L[1][j]); w_.y = pk2(L[2][j], L[3][j]); \
        w_.z = pk2(L[4][j], L[5][j]); w_.w = pk2(L[6][j], L[7][j]); \
        *(uint4*)(smem + boff_ + waddr[j]) = w_; } }
#define COMPUTE(buf) { const int boff_ = (buf) * 32768; \
    _Pragma("unroll") for (int kk = 0; kk < 2; ++kk) { \
        bf16x8 a0_ = *(const bf16x8*)(smem + boff_ + raddrA[kk][0]); \
        bf16x8 a1_ = *(const bf16x8*)(smem + boff_ + raddrA[kk][1]); \
        bf16x8 b0_ = *(const bf16x8*)(smem + boff_ + raddrB[kk][0]); \
        bf16x8 b1_ = *(const bf16x8*)(smem + boff_ + raddrB[kk][1]); \
        acc[0][0] = __builtin_amdgcn_mfma_f32_32x32x16_bf16(a0_, b0_, acc[0][0], 0, 0, 0); \
        acc[0][1] = __builtin_amdgcn_mfma_f32_32x32x16_bf16(a0_, b1_, acc[0][1], 0, 0, 0); \
        acc[1][0] = __builtin_amdgcn_mfma_f32_32x32x16_bf16(a1_, b0_, acc[1][0], 0, 0, 0); \
        acc[1][1] = __builtin_amdgcn_mfma_f32_32x32x16_bf16(a1_, b1_, acc[1][1], 0, 0, 0); } }
    LOAD_TILE(0);
    for (int k = 0; k < NK; ++k) {
        WRITE_TILE(k & 1);
        if (k + 1 < NK) LOAD_TILE(k + 1);
        __syncthreads();
        COMPUTE(k & 1);
    }
#undef LOAD_TILE
#undef WRITE_TILE
#undef COMPUTE
    __syncthreads();
    if (h == 1) {
#pragma unroll
        for (int m2 = 0; m2 < 2; ++m2)
#pragma unroll
            for (int n2 = 0; n2 < 2; ++n2) {
                unsigned char* base = smem + (wave - 4) * 16384 + (m2 * 2 + n2) * 4096 + lane * 16;
#pragma unroll
                for (int r4 = 0; r4 < 4; ++r4) {
                    f32x4 v = { acc[m2][n2][r4 * 4 + 0], acc[m2][n2][r4 * 4 + 1],
                                acc[m2][n2][r4 * 4 + 2], acc[m2][n2][r4 * 4 + 3] };
                    *(f32x4*)(base + r4 * 1024) = v;
                }
            }
    }
    __syncthreads();
    if (h == 0) {
#pragma unroll
        for (int m2 = 0; m2 < 2; ++m2)
#pragma unroll
            for (int n2 = 0; n2 < 2; ++n2) {
                const unsigned char* base = smem + wave * 16384 + (m2 * 2 + n2) * 4096 + lane * 16;
#pragma unroll
                for (int r4 = 0; r4 < 4; ++r4) {
                    f32x4 v = *(const f32x4*)(base + r4 * 1024);
#pragma unroll
                    for (int j = 0; j < 4; ++j) acc[m2][n2][r4 * 4 + j] += v[j];
                }
            }
        const int s_w = mt * 128 + wm * 64;
        const int c_w = nt * 128 + wn * 64;
        float* outp = out + BC;
#pragma unroll
        for (int m2 = 0; m2 < 2; ++m2)
#pragma unroll
            for (int n2 = 0; n2 < 2; ++n2)
#pragma unroll
                for (int r = 0; r < 16; ++r) {
                    const int row = (r & 3) + 8 * (r >> 2) + 4 * kg;
                    outp[(size_t)(s_w + m2 * 32 + row) * BC + b * C + c_w + n2 * 32 + lm]
                        = acc[m2][n2][r];
                }
    }
}

extern "C" void kernel_launch(void* const* d_in, const int* in_sizes, int n_in,
                              void* d_out, int out_size, void* d_ws, size_t ws_size,
                              hipStream_t stream) {
    const float* x    = (const float*)d_in[0];  // [T,B,C] fp32
    const float* mask = (const float*)d_in[1];  // [B,T,S] fp32
    const float* left = (const float*)d_in[3];  // [1,1,C] fp32
    float* out = (float*)d_out;                 // [S+1,B,C] fp32

    left_fill<<<BC / 256, 256, 0, stream>>>(left, out);

    const size_t XT_BYTES = (size_t)T * Bb * C * sizeof(__bf16);  // 32 MiB
    if (ws_size >= XT_BYTES) {
        __bf16* xT = (__bf16*)d_ws;
        transpose_x<<<Bb * (T / 64) * (C / 64), 256, 0, stream>>>(x, xT);
        ds_gemm_direct<<<Bb * (S / 128) * (C / 128), 512, 0, stream>>>(xT, mask, out);
    } else {
        ds_gemm_fb<<<Bb * (S / 128) * (C / 128), 512, 0, stream>>>(x, mask, out);
    }
}

// Round 15
// 141.233 us; speedup vs baseline: 2.3359x; 1.5342x over previous
//
#include <hip/hip_runtime.h>
#include <hip/hip_bf16.h>
#include <stdint.h>

// Problem constants (fixed by the reference).
constexpr int T  = 4096;   // contraction dim (K = t)
constexpr int Bb = 8;      // batch
constexpr int C  = 512;    // channels (N)
constexpr int S  = 2048;   // groups (M)
constexpr int BC = Bb * C; // 4096 floats: t-row stride of x, s-row stride of out

constexpr int BK = 64;        // K-tile per iteration
constexpr int NK = T / BK;    // 64 iterations

typedef __bf16 bf16x8 __attribute__((ext_vector_type(8)));
typedef float  f32x16 __attribute__((ext_vector_type(16)));
typedef float  f32x4  __attribute__((ext_vector_type(4)));
typedef unsigned int u32;

__device__ inline unsigned pk2(float lo, float hi) {
    union { __hip_bfloat16 h; unsigned short u; } a, b;
    a.h = __float2bfloat16(lo);
    b.h = __float2bfloat16(hi);
    return ((unsigned)b.u << 16) | (unsigned)a.u;
}

__device__ inline int slot16(int s) { return s ^ ((s >> 2) & 7); }

// global -> LDS direct DMA, 16B per lane. LDS dest is wave-uniform base +
// lane*16 (m104); global src is per-lane. AS casts via uintptr (CK pattern;
// low 32 bits of a generic LDS pointer are the LDS offset).
__device__ inline void glds16(const void* g, void* l) {
    __builtin_amdgcn_global_load_lds(
        (const u32 __attribute__((address_space(1)))*)(uintptr_t)g,
        (u32 __attribute__((address_space(3)))*)(u32)(uintptr_t)l,
        16, 0, 0);
}

// out[0,b,c] = leftmost[c]
__global__ void left_fill(const float* __restrict__ left, float* __restrict__ out) {
    int i = blockIdx.x * blockDim.x + threadIdx.x;
    if (i < BC) out[i] = left[i & (C - 1)];
}

// Pre-pass: write x as bf16 in the EXACT B-LDS tile image:
// xTile[b][nt][k][byte], byte = oct*2048 + cc*16 + j*2 holding
// x[t = k*64+oct*8+j][b][c = nt*128+cc]. 32 MiB total; ~96MB traffic.
// (r14's transpose verified correct; only the store indexing changed.)
__global__ __launch_bounds__(256) void transpose_x(
    const float* __restrict__ x, __bf16* __restrict__ xT)
{
    __shared__ float lds[64][68];      // padded fp32 64x64 tile
    const int bid = blockIdx.x;        // 8 b x 64 k x 8 c-tiles = 4096
    const int b   = bid >> 9;
    const int rem = bid & 511;
    const int t0  = (rem >> 3) * 64;
    const int c0  = (rem & 7) * 64;
    const int tid = threadIdx.x;

#pragma unroll
    for (int it = 0; it < 4; ++it) {
        const int slot = tid + it * 256;          // 64 rows x 16 colgroups
        const int row = slot >> 4, cg = slot & 15;
        f32x4 v = *(const f32x4*)(x + (size_t)(t0 + row) * BC + b * C + c0 + cg * 4);
        *(f32x4*)(&lds[row][cg * 4]) = v;
    }
    __syncthreads();
    const int k = t0 >> 6;
#pragma unroll
    for (int it = 0; it < 2; ++it) {
        const int slot = tid + it * 256;          // 8 t-octs x 64 cols
        const int tg8 = slot >> 6, cr = slot & 63;
        const int c  = c0 + cr;
        const int nt = c >> 7, cc = c & 127;
        uint4 w;
        w.x = pk2(lds[tg8 * 8 + 0][cr], lds[tg8 * 8 + 1][cr]);
        w.y = pk2(lds[tg8 * 8 + 2][cr], lds[tg8 * 8 + 3][cr]);
        w.z = pk2(lds[tg8 * 8 + 4][cr], lds[tg8 * 8 + 5][cr]);
        w.w = pk2(lds[tg8 * 8 + 6][cr], lds[tg8 * 8 + 7][cr]);
        // element (bf16) offset: tile base + tg8*1024 + cc*8
        *(uint4*)(xT + ((size_t)(b * 4 + nt) * 64 + k) * 8192 + tg8 * 1024 + cc * 8) = w;
    }
}

// MAIN (round 15) = r8 (142us champion: 128x128, BK=64, 8 waves h-split K,
// 2 blocks/CU, XCD swizzle) with the B operand staged by global_load_lds
// DMA from the pre-tiled bf16 image: zero B registers, zero pack, zero
// ds_write instructions for B. m97-order loop, one raw barrier per iter:
//   GLDS_B(k+1) ; LOAD_A(k+1) ; COMPUTE(k) ; WRITE_A(k+1) [pack's vmcnt
//   drains loadA(k+1)+gldsB(k+1), both covered by COMPUTE(k)] ; lgkm(0) ;
//   raw s_barrier.
// Race audit (2+2 buffers): all reads of buf X at COMPUTE(k-1) happen
// before barrier(end k-1) and are lgkm-drained there; any write to X at
// iter k (glds or ds_write) is issued after that barrier. COMPUTE(k)'s
// sources: bufA[k&1] written+lgkm'd before barrier(k-1); bufB[k&1] DMA'd
// by gldsB(k) whose vmcnt drain (pack, iter k-1) precedes barrier(k-1).
__global__ __launch_bounds__(512, 4) void ds_gemm_glds(
    const __bf16* __restrict__ xT,
    const float* __restrict__ mask,
    float* __restrict__ out)
{
    __shared__ __align__(16) unsigned char smem[65536];  // A: 2x16KB | B: 2x16KB

    const int bid0 = blockIdx.x;
    const int xcd  = bid0 & 7;
    const int slot = bid0 >> 3;
    const int b    = xcd;                 // batch plane owned by this XCD
    const int mt   = slot & 15;           // s-tile
    const int nt   = (slot >> 4) & 3;     // c-tile

    const int tid  = threadIdx.x;
    const int lane = tid & 63;
    const int wave = tid >> 6;       // 0..7
    const int h    = wave >> 2;      // K-group (0..1)
    const int wq   = wave & 3;
    const int wm = wq >> 1;          // s-half
    const int wn = wq & 1;           // c-half
    const int lm = lane & 31;
    const int kg = lane >> 5;

    // ---- A (mask) reg-staging: threads 0-255, r8's exact shape ----
    const int ii = tid & 255, sg = ii & 31, tg = ii >> 5;
    const float* gsrc = mask + (size_t)b * T * S + (size_t)(tg * 8) * S + mt * 128 + sg * 4;
    const size_t gstep = (size_t)S * BK;

    int waddr[4];
#pragma unroll
    for (int j = 0; j < 4; ++j)
        waddr[j] = tg * 2048 + slot16(sg * 4 + j) * 16;

    // ---- fragment addresses (oct = h*4 + kk*2 + kg) ----
    int raddrA[2][2], roffB[2][2];
#pragma unroll
    for (int kk = 0; kk < 2; ++kk)
#pragma unroll
        for (int q = 0; q < 2; ++q) {
            const int oct = h * 4 + kk * 2 + kg;
            raddrA[kk][q] = oct * 2048 + slot16(wm * 64 + q * 32 + lm) * 16;
            roffB[kk][q]  = oct * 2048 + (wn * 64 + q * 32 + lm) * 16;  // linear image
        }

    // ---- B global tile base (this block's b,nt panel) ----
    const char* xtile = (const char*)(xT + ((size_t)(b * 4 + nt) * 64) * 8192);

    f32x16 acc[2][2] = {};
    f32x4  L[8];

#define LOAD_A(k)                                                           \
    if (tid < 256) {                                                        \
        const float* p_ = gsrc + (size_t)(k) * gstep;                       \
        _Pragma("unroll") for (int r = 0; r < 8; ++r)                       \
            L[r] = *(const f32x4*)(p_ + (size_t)r * S);                     \
    }

#define WRITE_A(buf)                                                        \
    if (tid < 256) {                                                        \
        const int boff_ = (buf) * 16384;                                    \
        _Pragma("unroll") for (int j = 0; j < 4; ++j) {                     \
            uint4 w_;                                                       \
            w_.x = pk2(L[0][j], L[1][j]);                                   \
            w_.y = pk2(L[2][j], L[3][j]);                                   \
            w_.z = pk2(L[4][j], L[5][j]);                                   \
            w_.w = pk2(L[6][j], L[7][j]);                                   \
            *(uint4*)(smem + boff_ + waddr[j]) = w_;                        \
        }                                                                   \
    }

// 16KB B tile via 2 glds rounds: wave wv covers bytes [wv*1024, +1KB) and
// [8192+wv*1024, +1KB); lds dest = wave-uniform base (+lane*16 by HW),
// global src per-lane matches the same linear order.
#define GLDS_B(k)                                                           \
    {                                                                       \
        const char* gb_ = xtile + (size_t)(k) * 16384;                      \
        char* lb_ = (char*)smem + 32768 + ((k) & 1) * 16384 + wave * 1024;  \
        glds16(gb_ + tid * 16,        lb_);                                 \
        glds16(gb_ + tid * 16 + 8192, lb_ + 8192);                          \
    }

#define COMPUTE(k)                                                          \
    {                                                                       \
        const int ba_ = ((k) & 1) * 16384;                                  \
        const int bb_ = 32768 + ((k) & 1) * 16384;                          \
        _Pragma("unroll") for (int kk = 0; kk < 2; ++kk) {                  \
            bf16x8 a0_ = *(const bf16x8*)(smem + ba_ + raddrA[kk][0]);      \
            bf16x8 a1_ = *(const bf16x8*)(smem + ba_ + raddrA[kk][1]);      \
            bf16x8 b0_ = *(const bf16x8*)(smem + bb_ + roffB[kk][0]);       \
            bf16x8 b1_ = *(const bf16x8*)(smem + bb_ + roffB[kk][1]);       \
            acc[0][0] = __builtin_amdgcn_mfma_f32_32x32x16_bf16(a0_, b0_, acc[0][0], 0, 0, 0); \
            acc[0][1] = __builtin_amdgcn_mfma_f32_32x32x16_bf16(a0_, b1_, acc[0][1], 0, 0, 0); \
            acc[1][0] = __builtin_amdgcn_mfma_f32_32x32x16_bf16(a1_, b0_, acc[1][0], 0, 0, 0); \
            acc[1][1] = __builtin_amdgcn_mfma_f32_32x32x16_bf16(a1_, b1_, acc[1][1], 0, 0, 0); \
        }                                                                   \
    }

    // Prologue: stage tile 0 (full drain once is fine).
    GLDS_B(0);
    LOAD_A(0);
    WRITE_A(0);            // vmcnt drain covers gldsB(0) too (older)
    __syncthreads();

    for (int k = 0; k < NK; ++k) {
        if (k + 1 < NK) {
            GLDS_B(k + 1);                 // DMA in flight through COMPUTE(k)
            LOAD_A(k + 1);                 // reg loads in flight through COMPUTE(k)
        }
        COMPUTE(k);
        if (k + 1 < NK) WRITE_A((k + 1) & 1);  // pack: waits loadA(k+1)+gldsB(k+1)
        asm volatile("s_waitcnt lgkmcnt(0)" ::: "memory");   // ds_writes visible
        __builtin_amdgcn_s_barrier();                         // raw: no vmcnt drain
        __builtin_amdgcn_sched_barrier(0);
    }

#undef LOAD_A
#undef WRITE_A
#undef GLDS_B
#undef COMPUTE

    // -------- cross-K-group reduction via LDS, then store (h=0 only) --------
    __syncthreads();
    if (h == 1) {
#pragma unroll
        for (int m2 = 0; m2 < 2; ++m2)
#pragma unroll
            for (int n2 = 0; n2 < 2; ++n2) {
                unsigned char* base = smem + (wave - 4) * 16384 + (m2 * 2 + n2) * 4096 + lane * 16;
#pragma unroll
                for (int r4 = 0; r4 < 4; ++r4) {
                    f32x4 v = { acc[m2][n2][r4 * 4 + 0], acc[m2][n2][r4 * 4 + 1],
                                acc[m2][n2][r4 * 4 + 2], acc[m2][n2][r4 * 4 + 3] };
                    *(f32x4*)(base + r4 * 1024) = v;
                }
            }
    }
    __syncthreads();
    if (h == 0) {
#pragma unroll
        for (int m2 = 0; m2 < 2; ++m2)
#pragma unroll
            for (int n2 = 0; n2 < 2; ++n2) {
                const unsigned char* base = smem + wave * 16384 + (m2 * 2 + n2) * 4096 + lane * 16;
#pragma unroll
                for (int r4 = 0; r4 < 4; ++r4) {
                    f32x4 v = *(const f32x4*)(base + r4 * 1024);
#pragma unroll
                    for (int j = 0; j < 4; ++j) acc[m2][n2][r4 * 4 + j] += v[j];
                }
            }
        const int s_w = mt * 128 + wm * 64;
        const int c_w = nt * 128 + wn * 64;
        float* outp = out + BC;
#pragma unroll
        for (int m2 = 0; m2 < 2; ++m2)
#pragma unroll
            for (int n2 = 0; n2 < 2; ++n2)
#pragma unroll
                for (int r = 0; r < 16; ++r) {
                    const int row = (r & 3) + 8 * (r >> 2) + 4 * kg;
                    outp[(size_t)(s_w + m2 * 32 + row) * BC + b * C + c_w + n2 * 32 + lm]
                        = acc[m2][n2][r];
                }
    }
}

// ---------- FALLBACK (ws too small): round-8 champion kernel verbatim ----------
__global__ __launch_bounds__(512, 4) void ds_gemm_fb(
    const float* __restrict__ x, const float* __restrict__ mask, float* __restrict__ out)
{
    __shared__ __align__(16) unsigned char smem[65536];
    const int bid0 = blockIdx.x;
    const int xcd = bid0 & 7, slot = bid0 >> 3;
    const int b = xcd, mt = slot & 15, nt = (slot >> 4) & 3;
    const int tid = threadIdx.x, lane = tid & 63, wave = tid >> 6;
    const int h = wave >> 2, wq = wave & 3, wm = wq >> 1, wn = wq & 1;
    const int lm = lane & 31, kg = lane >> 5;
    const int ii = tid & 255, sg = ii & 31, tg = ii >> 5;
    const bool stB = (tid >= 256);
    const float* gsrc = stB
        ? x    + (size_t)(tg * 8) * BC + b * C + nt * 128 + sg * 4
        : mask + (size_t)b * T * S + (size_t)(tg * 8) * S + mt * 128 + sg * 4;
    const size_t grow = stB ? (size_t)BC : (size_t)S;
    const size_t gstep = grow * BK;
    int waddr[4];
#pragma unroll
    for (int j = 0; j < 4; ++j)
        waddr[j] = (stB ? 16384 : 0) + tg * 2048 + slot16(sg * 4 + j) * 16;
    int raddrA[2][2], raddrB[2][2];
#pragma unroll
    for (int kk = 0; kk < 2; ++kk)
#pragma unroll
        for (int q = 0; q < 2; ++q) {
            const int oct = h * 4 + kk * 2 + kg;
            raddrA[kk][q] = oct * 2048 + slot16(wm * 64 + q * 32 + lm) * 16;
            raddrB[kk][q] = 16384 + oct * 2048 + slot16(wn * 64 + q * 32 + lm) * 16;
        }
    f32x16 acc[2][2] = {};
    f32x4 L[8];
#define LOAD_TILE(k) { const float* p_ = gsrc + (size_t)(k) * gstep; \
    _Pragma("unroll") for (int r = 0; r < 8; ++r) L[r] = *(const f32x4*)(p_ + (size_t)r * grow); }
#define WRITE_TILE(buf) { const int boff_ = (buf) * 32768; \
    _Pragma("unroll") for (int j = 0; j < 4; ++j) { uint4 w_; \
        w_.x = pk2(L[0][j], L[1][j]); w_.y = pk2(L[2][j], L[3][j]); \
        w_.z = pk2(L[4][j], L[5][j]); w_.w = pk2(L[6][j], L[7][j]); \
        *(uint4*)(smem + boff_ + waddr[j]) = w_; } }
#define COMPUTE(buf) { const int boff_ = (buf) * 32768; \
    _Pragma("unroll") for (int kk = 0; kk < 2; ++kk) { \
        bf16x8 a0_ = *(const bf16x8*)(smem + boff_ + raddrA[kk][0]); \
        bf16x8 a1_ = *(const bf16x8*)(smem + boff_ + raddrA[kk][1]); \
        bf16x8 b0_ = *(const bf16x8*)(smem + boff_ + raddrB[kk][0]); \
        bf16x8 b1_ = *(const bf16x8*)(smem + boff_ + raddrB[kk][1]); \
        acc[0][0] = __builtin_amdgcn_mfma_f32_32x32x16_bf16(a0_, b0_, acc[0][0], 0, 0, 0); \
        acc[0][1] = __builtin_amdgcn_mfma_f32_32x32x16_bf16(a0_, b1_, acc[0][1], 0, 0, 0); \
        acc[1][0] = __builtin_amdgcn_mfma_f32_32x32x16_bf16(a1_, b0_, acc[1][0], 0, 0, 0); \
        acc[1][1] = __builtin_amdgcn_mfma_f32_32x32x16_bf16(a1_, b1_, acc[1][1], 0, 0, 0); } }
    LOAD_TILE(0);
    for (int k = 0; k < NK; ++k) {
        WRITE_TILE(k & 1);
        if (k + 1 < NK) LOAD_TILE(k + 1);
        __syncthreads();
        COMPUTE(k & 1);
    }
#undef LOAD_TILE
#undef WRITE_TILE
#undef COMPUTE
    __syncthreads();
    if (h == 1) {
#pragma unroll
        for (int m2 = 0; m2 < 2; ++m2)
#pragma unroll
            for (int n2 = 0; n2 < 2; ++n2) {
                unsigned char* base = smem + (wave - 4) * 16384 + (m2 * 2 + n2) * 4096 + lane * 16;
#pragma unroll
                for (int r4 = 0; r4 < 4; ++r4) {
                    f32x4 v = { acc[m2][n2][r4 * 4 + 0], acc[m2][n2][r4 * 4 + 1],
                                acc[m2][n2][r4 * 4 + 2], acc[m2][n2][r4 * 4 + 3] };
                    *(f32x4*)(base + r4 * 1024) = v;
                }
            }
    }
    __syncthreads();
    if (h == 0) {
#pragma unroll
        for (int m2 = 0; m2 < 2; ++m2)
#pragma unroll
            for (int n2 = 0; n2 < 2; ++n2) {
                const unsigned char* base = smem + wave * 16384 + (m2 * 2 + n2) * 4096 + lane * 16;
#pragma unroll
                for (int r4 = 0; r4 < 4; ++r4) {
                    f32x4 v = *(const f32x4*)(base + r4 * 1024);
#pragma unroll
                    for (int j = 0; j < 4; ++j) acc[m2][n2][r4 * 4 + j] += v[j];
                }
            }
        const int s_w = mt * 128 + wm * 64;
        const int c_w = nt * 128 + wn * 64;
        float* outp = out + BC;
#pragma unroll
        for (int m2 = 0; m2 < 2; ++m2)
#pragma unroll
            for (int n2 = 0; n2 < 2; ++n2)
#pragma unroll
                for (int r = 0; r < 16; ++r) {
                    const int row = (r & 3) + 8 * (r >> 2) + 4 * kg;
                    outp[(size_t)(s_w + m2 * 32 + row) * BC + b * C + c_w + n2 * 32 + lm]
                        = acc[m2][n2][r];
                }
    }
}

extern "C" void kernel_launch(void* const* d_in, const int* in_sizes, int n_in,
                              void* d_out, int out_size, void* d_ws, size_t ws_size,
                              hipStream_t stream) {
    const float* x    = (const float*)d_in[0];  // [T,B,C] fp32
    const float* mask = (const float*)d_in[1];  // [B,T,S] fp32
    const float* left = (const float*)d_in[3];  // [1,1,C] fp32
    float* out = (float*)d_out;                 // [S+1,B,C] fp32

    left_fill<<<BC / 256, 256, 0, stream>>>(left, out);

    const size_t XT_BYTES = (size_t)T * Bb * C * sizeof(__bf16);  // 32 MiB
    if (ws_size >= XT_BYTES) {
        __bf16* xT = (__bf16*)d_ws;
        transpose_x<<<Bb * (T / 64) * (C / 64), 256, 0, stream>>>(x, xT);
        ds_gemm_glds<<<Bb * (S / 128) * (C / 128), 512, 0, stream>>>(xT, mask, out);
    } else {
        ds_gemm_fb<<<Bb * (S / 128) * (C / 128), 512, 0, stream>>>(x, mask, out);
    }
}